// Round 13
// baseline (235.400 us; speedup 1.0000x reference)
//
#include <hip/hip_runtime.h>
#include <hip/hip_bf16.h>

#define N_NODES 8192
#define E_EDGES 65536
#define CDIM 384
#define NHC 1152
#define T_STEPS 12
#define PRED_LEN 6
#define OUT_LABEL_OFF 49152

#define O_X        0u
#define O_WIH      1572864u
#define O_WHH      1574400u
#define O_BIH      1577472u
#define O_BHH      1577568u
#define O_WGAT     1577664u
#define O_ATTS     2020032u
#define O_ATTD     2021184u
#define O_WEDGE    2022336u
#define O_ATTE     2023488u
#define O_GBIAS    2024640u
#define O_WP1      2025024u
#define O_BP1      2025056u
#define O_WP3      2025057u
#define O_BP3      2025129u
#define O_WC1      2025135u
#define O_BC1      2037423u
#define O_WC2      2037455u
#define O_BC2      2037519u
#define O_EATTR    2037521u
#define CONV_TOTAL 2103057u

#define O_GATIN    2103072u
#define O_GATB     O_GATIN
#define O_WGATB    (O_GATIN + 1572864u)
#define O_DEG      (O_GATIN + 1794048u)   // int [8192]
#define O_HFEAT    5248800u
#define O_ASRC     14685984u
#define O_ADST     14710560u
#define O_WEXP     14931744u
#define O_DENOM    15152928u
#define O_GMEAN    15177504u
#define O_POOLED   18323232u
#define O_KH       18326304u
#define O_FLAG     18326307u
#define O_BUCKET   18326320u              // int [8192*64]

typedef __attribute__((ext_vector_type(8))) short short8;
typedef __attribute__((ext_vector_type(4))) float floatx4;

__device__ __forceinline__ float b2f(unsigned short u) {
    return __uint_as_float(((unsigned)u) << 16);
}
__device__ __forceinline__ unsigned short f2b(float f) {
    __hip_bfloat16 b = __float2bfloat16(f);
    return *(unsigned short*)&b;
}
__device__ __forceinline__ short f2bs(float f) {
    __hip_bfloat16 b = __float2bfloat16(f);
    return *(short*)&b;
}
__device__ __forceinline__ unsigned enc_f(float f) {
    unsigned u = __float_as_uint(f);
    return (u & 0x80000000u) ? ~u : (u | 0x80000000u);
}
__device__ __forceinline__ float dec_f(unsigned e) {
    return __uint_as_float((e & 0x80000000u) ? (e & 0x7FFFFFFFu) : ~e);
}
__device__ __forceinline__ float fast_rcp(float x) {
    return __builtin_amdgcn_rcpf(x);
}

// ------------------------------------------------ prep: detect + zero + convert + Kh
__global__ __launch_bounds__(256) void prep_kernel(
    const void* Wih, const void* Whh, const void* bih, const void* bhh,
    const void* Wgat, const void* atts, const void* attd, const void* Wedge, const void* atte,
    const void* gbias, const void* Wp1, const void* bp1, const void* Wp3, const void* bp3,
    const void* Wc1, const void* bc1, const void* Wc2, const void* bc2, const void* eattr,
    float* __restrict__ W, unsigned short* __restrict__ wgatb, int* __restrict__ flag_g)
{
    __shared__ int fsh;
    if (threadIdx.x < 64) {
        int lane = threadIdx.x, cnt = 0;
#pragma unroll
        for (int i = 0; i < 8; i++) {
            unsigned short h = ((const unsigned short*)Wih)[(lane * 8 + i) * 2];
            int e = (h >> 7) & 0xFF;
            if (e >= 100 && e <= 127) cnt++;
        }
#pragma unroll
        for (int off = 32; off; off >>= 1) cnt += __shfl_down(cnt, off, 64);
        if (lane == 0) fsh = (cnt >= 300) ? 1 : 0;
    }
    __syncthreads();
    int flag = fsh;
    unsigned tidg = blockIdx.x * 256 + threadIdx.x;
    if (tidg == 0) *flag_g = flag;

    // Kh: block 0, threads 0..191 (3 heads x 64 lanes) from raw Wedge/att_edge
    if (blockIdx.x == 0 && threadIdx.x < 192) {
        int hd = threadIdx.x >> 6, lane = threadIdx.x & 63;
        float s = 0.f;
#pragma unroll
        for (int qq = 0; qq < 6; qq++) {
            int c = hd * CDIM + lane + qq * 64;
            float we = flag ? b2f(((const unsigned short*)Wedge)[c]) : ((const float*)Wedge)[c];
            float ae = flag ? b2f(((const unsigned short*)atte)[c])  : ((const float*)atte)[c];
            s += we * ae;
        }
#pragma unroll
        for (int off = 32; off; off >>= 1) s += __shfl_down(s, off, 64);
        if (lane == 0) W[O_KH + hd] = s;
    }

    // zero: denom 24576 + pooled 3072 + deg 8192 + a_src 24576 + a_dst 24576
    if      (tidg < 24576u) W[O_DENOM + tidg] = 0.f;
    else if (tidg < 27648u) W[O_POOLED + tidg - 24576u] = 0.f;
    else if (tidg < 35840u) ((int*)(W + O_DEG))[tidg - 27648u] = 0;
    else if (tidg < 60416u) W[O_ASRC + tidg - 35840u] = 0.f;
    else if (tidg < 84992u) W[O_ADST + tidg - 60416u] = 0.f;

    unsigned idx = tidg + O_WIH;
    if (idx >= CONV_TOTAL) return;
    if (idx >= O_WGAT && idx < O_ATTS) {
        unsigned off = idx - O_WGAT;
        wgatb[off] = flag ? ((const unsigned short*)Wgat)[off]
                          : f2b(((const float*)Wgat)[off]);
        return;
    }
    const void* src; unsigned off;
    if      (idx < O_WHH)   { src = Wih;   off = idx - O_WIH; }
    else if (idx < O_BIH)   { src = Whh;   off = idx - O_WHH; }
    else if (idx < O_BHH)   { src = bih;   off = idx - O_BIH; }
    else if (idx < O_WGAT)  { src = bhh;   off = idx - O_BHH; }
    else if (idx < O_ATTD)  { src = atts;  off = idx - O_ATTS; }
    else if (idx < O_WEDGE) { src = attd;  off = idx - O_ATTD; }
    else if (idx < O_ATTE)  { src = Wedge; off = idx - O_WEDGE; }
    else if (idx < O_GBIAS) { src = atte;  off = idx - O_ATTE; }
    else if (idx < O_WP1)   { src = gbias; off = idx - O_GBIAS; }
    else if (idx < O_BP1)   { src = Wp1;   off = idx - O_WP1; }
    else if (idx < O_BP3)   { src = (idx == O_BP1) ? bp1 : Wp3; off = (idx == O_BP1) ? 0 : idx - O_WP3; }
    else if (idx < O_WC1)   { src = bp3;   off = idx - O_BP3; }
    else if (idx < O_BC1)   { src = Wc1;   off = idx - O_WC1; }
    else if (idx < O_WC2)   { src = bc1;   off = idx - O_BC1; }
    else if (idx < O_BC2)   { src = Wc2;   off = idx - O_WC2; }
    else if (idx < O_EATTR) { src = bc2;   off = idx - O_BC2; }
    else                    { src = eattr; off = idx - O_EATTR; }
    W[idx] = flag ? b2f(((const unsigned short*)src)[off])
                  : ((const float*)src)[off];
}

// ------------------------------------------------ MFMA GRU: one wave = 16 nodes (validated R8+)
__global__ __launch_bounds__(64, 1) void gru_kernel(
    const float* __restrict__ W,
    const void* __restrict__ xraw,
    unsigned short* __restrict__ gat_b)
{
    __shared__ short hbuf[16 * 40];
    int lane = threadIdx.x;
    int q = lane >> 4, nl = lane & 15;
    int n0 = blockIdx.x * 16;
    int n = n0 + nl;
    int flag = ((const int*)(W + O_FLAG))[0];

    const float* W_wih = W + O_WIH;
    const float* W_whh = W + O_WHH;
    const float* W_bih = W + O_BIH;
    const float* W_bhh = W + O_BHH;

    short8 wh[6], wi[6];
#pragma unroll
    for (int c = 0; c < 6; c++) {
        int row = c * 16 + nl;
#pragma unroll
        for (int r = 0; r < 8; r++) {
            wh[c][r] = f2bs(W_whh[row * 32 + 8 * q + r]);
            int k = 8 * q + r;
            wi[c][r] = (k < 16) ? f2bs(W_wih[row * 16 + k]) : (short)0;
        }
    }
    float br[8], bz[8], bni[8], bnh[8];
#pragma unroll
    for (int idx = 0; idx < 8; idx++) {
        int c = idx >> 2, r = idx & 3;
        int j = c * 16 + 4 * q + r;
        br[idx]  = W_bih[j] + W_bhh[j];
        bz[idx]  = W_bih[32 + j] + W_bhh[32 + j];
        bni[idx] = W_bih[64 + j];
        bnh[idx] = W_bhh[64 + j];
    }

    floatx4 zf = {0.f, 0.f, 0.f, 0.f};
    short8 zs;
#pragma unroll
    for (int r = 0; r < 8; r++) zs[r] = 0;

    float hprev[8];
#pragma unroll
    for (int i = 0; i < 8; i++) hprev[i] = 0.f;
    short8 hfrag = zs;

    for (int t = 0; t < T_STEPS; t++) {
        short8 xf = zs;
        if (q < 2) {
            size_t xoff = (size_t)n * 192 + t * 16 + 8 * q;
            if (flag) {
                xf = *(const short8*)((const unsigned short*)xraw + xoff);
            } else {
                const float* xp = (const float*)xraw + xoff;
                float4 xa = *(const float4*)xp;
                float4 xb = *(const float4*)(xp + 4);
                xf[0] = f2bs(xa.x); xf[1] = f2bs(xa.y); xf[2] = f2bs(xa.z); xf[3] = f2bs(xa.w);
                xf[4] = f2bs(xb.x); xf[5] = f2bs(xb.y); xf[6] = f2bs(xb.z); xf[7] = f2bs(xb.w);
            }
        }

        floatx4 aR0 = __builtin_amdgcn_mfma_f32_16x16x32_bf16(wi[0], xf, zf, 0, 0, 0);
        aR0 = __builtin_amdgcn_mfma_f32_16x16x32_bf16(wh[0], hfrag, aR0, 0, 0, 0);
        floatx4 aR1 = __builtin_amdgcn_mfma_f32_16x16x32_bf16(wi[1], xf, zf, 0, 0, 0);
        aR1 = __builtin_amdgcn_mfma_f32_16x16x32_bf16(wh[1], hfrag, aR1, 0, 0, 0);
        floatx4 aZ0 = __builtin_amdgcn_mfma_f32_16x16x32_bf16(wi[2], xf, zf, 0, 0, 0);
        aZ0 = __builtin_amdgcn_mfma_f32_16x16x32_bf16(wh[2], hfrag, aZ0, 0, 0, 0);
        floatx4 aZ1 = __builtin_amdgcn_mfma_f32_16x16x32_bf16(wi[3], xf, zf, 0, 0, 0);
        aZ1 = __builtin_amdgcn_mfma_f32_16x16x32_bf16(wh[3], hfrag, aZ1, 0, 0, 0);
        floatx4 aNI0 = __builtin_amdgcn_mfma_f32_16x16x32_bf16(wi[4], xf, zf, 0, 0, 0);
        floatx4 aNI1 = __builtin_amdgcn_mfma_f32_16x16x32_bf16(wi[5], xf, zf, 0, 0, 0);
        floatx4 aNH0 = __builtin_amdgcn_mfma_f32_16x16x32_bf16(wh[4], hfrag, zf, 0, 0, 0);
        floatx4 aNH1 = __builtin_amdgcn_mfma_f32_16x16x32_bf16(wh[5], hfrag, zf, 0, 0, 0);

#pragma unroll
        for (int idx = 0; idx < 8; idx++) {
            int c = idx >> 2, r = idx & 3;
            float vR = (c ? aR1[r] : aR0[r]) + br[idx];
            float vZ = (c ? aZ1[r] : aZ0[r]) + bz[idx];
            float vNI = (c ? aNI1[r] : aNI0[r]) + bni[idx];
            float vNH = (c ? aNH1[r] : aNH0[r]) + bnh[idx];
            float rr = fast_rcp(1.f + __expf(-vR));
            float zz = fast_rcp(1.f + __expf(-vZ));
            float pre = vNI + rr * vNH;
            float e2 = __expf(2.f * pre);
            float nn = 1.f - 2.f * fast_rcp(e2 + 1.f);
            float h = (1.f - zz) * nn + zz * hprev[idx];
            hprev[idx] = h;
            int j = c * 16 + 4 * q + r;
            hbuf[nl * 40 + j] = f2bs(h);
        }
        hfrag = *(short8*)&hbuf[nl * 40 + 8 * q];
        int sn = lane >> 2, jg = (lane & 3) * 8;
        short8 hv = *(short8*)&hbuf[sn * 40 + jg];
        *(short8*)(gat_b + (size_t)(n0 + sn) * 384 + t * 32 + jg) = hv;
    }
}

// ------------------------------------------------ MFMA GEMM + fused attention-score epilogue.
// 128 | 384 so each block's col range is in ONE head; per-row partial dots of C (f32, pre-
// rounding) with att vectors, shfl_xor-reduced over the 16 cn-lanes, one atomicAdd/(row,head).
__global__ __launch_bounds__(256) void gemm_mfma(
    const unsigned short* __restrict__ Ab,
    const unsigned short* __restrict__ Bb,
    unsigned short* __restrict__ Cb,
    const float* __restrict__ att_s,   // [1152]
    const float* __restrict__ att_d,   // [1152]
    float* __restrict__ a_src,         // [N*3]
    float* __restrict__ a_dst)         // [N*3]
{
    __shared__ unsigned short sA[128][40];
    __shared__ unsigned short sB[128][40];
    int tid = threadIdx.x;
    int wave = tid >> 6, lane = tid & 63;
    int wm = (wave >> 1) * 64, wn = (wave & 1) * 64;
    int m0 = blockIdx.x * 128, n0 = blockIdx.y * 128;

    int r0 = tid >> 2;
    int c8 = (tid & 3) * 8;

    floatx4 acc[4][4];
#pragma unroll
    for (int i = 0; i < 4; i++)
#pragma unroll
        for (int j = 0; j < 4; j++) acc[i][j] = 0;

    int ml = lane & 15, kq = (lane >> 4) * 8;

    for (int k0 = 0; k0 < 384; k0 += 32) {
        short8 a0 = *(const short8*)(Ab + (size_t)(m0 + r0) * 384 + k0 + c8);
        short8 a1 = *(const short8*)(Ab + (size_t)(m0 + r0 + 64) * 384 + k0 + c8);
        short8 b0 = *(const short8*)(Bb + (size_t)(n0 + r0) * 384 + k0 + c8);
        short8 b1 = *(const short8*)(Bb + (size_t)(n0 + r0 + 64) * 384 + k0 + c8);

        __syncthreads();
        *(short8*)(&sA[r0][c8])      = a0;
        *(short8*)(&sA[r0 + 64][c8]) = a1;
        *(short8*)(&sB[r0][c8])      = b0;
        *(short8*)(&sB[r0 + 64][c8]) = b1;
        __syncthreads();

        short8 af[4], bf[4];
#pragma unroll
        for (int i = 0; i < 4; i++)
            af[i] = *(const short8*)(&sA[wm + i * 16 + ml][kq]);
#pragma unroll
        for (int j = 0; j < 4; j++)
            bf[j] = *(const short8*)(&sB[wn + j * 16 + ml][kq]);
#pragma unroll
        for (int i = 0; i < 4; i++)
#pragma unroll
            for (int j = 0; j < 4; j++)
                acc[i][j] = __builtin_amdgcn_mfma_f32_16x16x32_bf16(af[i], bf[j], acc[i][j], 0, 0, 0);
    }

    int cn = lane & 15, rq = (lane >> 4) * 4;
#pragma unroll
    for (int i = 0; i < 4; i++)
#pragma unroll
        for (int j = 0; j < 4; j++)
#pragma unroll
            for (int r = 0; r < 4; r++)
                Cb[(size_t)(m0 + wm + i * 16 + rq + r) * NHC + n0 + wn + j * 16 + cn] = f2b(acc[i][j][r]);

    // fused attention-score epilogue
    int hd = n0 / CDIM;
    float avs[4], avd[4];
#pragma unroll
    for (int j = 0; j < 4; j++) {
        int c = n0 + wn + j * 16 + cn;
        avs[j] = att_s[c];
        avd[j] = att_d[c];
    }
#pragma unroll
    for (int i = 0; i < 4; i++) {
#pragma unroll
        for (int r = 0; r < 4; r++) {
            float s0 = acc[i][0][r] * avs[0] + acc[i][1][r] * avs[1]
                     + acc[i][2][r] * avs[2] + acc[i][3][r] * avs[3];
            float s1 = acc[i][0][r] * avd[0] + acc[i][1][r] * avd[1]
                     + acc[i][2][r] * avd[2] + acc[i][3][r] * avd[3];
#pragma unroll
            for (int m = 1; m < 16; m <<= 1) {
                s0 += __shfl_xor(s0, m, 64);
                s1 += __shfl_xor(s1, m, 64);
            }
            if (cn == 0) {
                int row = m0 + wm + i * 16 + rq + r;
                unsafeAtomicAdd(&a_src[row * 3 + hd], s0);
                unsafeAtomicAdd(&a_dst[row * 3 + hd], s1);
            }
        }
    }
}

// ------------------------------------------------ edge weights (exp w/o max — validated R10+)
// + denom + direct bucket fill (capacity 64; deg Poisson(8), P(>64) ~ 1e-37).
__global__ __launch_bounds__(256) void edge_w_kernel(
    const int* __restrict__ edge_index,
    const float* __restrict__ eattr,
    const float* __restrict__ a_src, const float* __restrict__ a_dst,
    const float* __restrict__ Kh,
    float* __restrict__ w_exp, float* __restrict__ denom,
    int* __restrict__ deg, int* __restrict__ bucket)
{
    int tid = blockIdx.x * 256 + threadIdx.x;
    int hd = tid >> 16;
    int e = tid & (E_EDGES - 1);
    int src = edge_index[e];
    int dst = edge_index[E_EDGES + e];
    float a = a_src[src * 3 + hd] + a_dst[dst * 3 + hd] + eattr[e] * Kh[hd];
    a = a > 0.f ? a : 0.2f * a;
    float w = __expf(a);
    w_exp[hd * E_EDGES + e] = w;
    unsafeAtomicAdd(&denom[dst * 3 + hd], w);
    if (hd == 0) {
        int pos = atomicAdd(&deg[dst], 1);
        if (pos < 64) bucket[(size_t)dst * 64 + pos] = e;
    }
}

// ------------------------------------------------ bucket aggregation + head-mean + predictor MLP
__global__ __launch_bounds__(384) void aggregate_fused(
    const int* __restrict__ flag,
    const int* __restrict__ edge_index,
    const unsigned short* __restrict__ h_bf,
    const float* __restrict__ w_exp, const float* __restrict__ denom,
    const int* __restrict__ deg, const int* __restrict__ bucket,
    const float* __restrict__ gat_bias,
    const float* __restrict__ Wp1, const float* __restrict__ bp1,
    const float* __restrict__ Wp3, const float* __restrict__ bp3,
    float* __restrict__ gmean,
    void* __restrict__ out_pred)
{
    int dst = blockIdx.x;
    int d = deg[dst]; if (d > 64) d = 64;
    int tid = threadIdx.x;
    const float third = 1.f / 3.f;
    float inv0 = third / (denom[dst * 3 + 0] + 1e-16f);
    float inv1 = third / (denom[dst * 3 + 1] + 1e-16f);
    float inv2 = third / (denom[dst * 3 + 2] + 1e-16f);
    __shared__ int ssrc[64];
    __shared__ float sc0[64], sc1[64], sc2[64];
    __shared__ float gs[384];
    __shared__ float ps[12];
    if (tid < d) {
        int e = bucket[(size_t)dst * 64 + tid];
        ssrc[tid] = edge_index[e];
        sc0[tid] = w_exp[e] * inv0;
        sc1[tid] = w_exp[E_EDGES + e] * inv1;
        sc2[tid] = w_exp[2 * E_EDGES + e] * inv2;
    }
    __syncthreads();
    float a = 0.f;
    for (int i = 0; i < d; i++) {
        const unsigned short* hs = h_bf + (size_t)ssrc[i] * NHC;
        a += sc0[i] * b2f(hs[tid]) + sc1[i] * b2f(hs[tid + CDIM]) + sc2[i] * b2f(hs[tid + 2 * CDIM]);
    }
    float g = a + gat_bias[tid];
    gmean[(size_t)dst * CDIM + tid] = g;
    gs[tid] = g;
    __syncthreads();

    int t = tid >> 5, c = tid & 31;
    float v = gs[t * 32 + c] * Wp1[c];
#pragma unroll
    for (int off = 16; off; off >>= 1) v += __shfl_down(v, off, 32);
    if (c == 0) { float p = v + bp1[0]; ps[t] = p > 0.f ? p : 0.f; }
    __syncthreads();

    if (tid < PRED_LEN) {
        float acc = bp3[tid];
#pragma unroll
        for (int tt = 0; tt < 12; tt++) acc += Wp3[tid * 12 + tt] * ps[tt];
        acc = acc > 0.f ? acc : 0.f;
        size_t oi = (size_t)dst * PRED_LEN + tid;
        if (*flag) ((__hip_bfloat16*)out_pred)[oi] = __float2bfloat16(acc);
        else       ((float*)out_pred)[oi] = acc;
    }
}

// ------------------------------------------------ two-stage batch max-pool (validated R4+)
__global__ __launch_bounds__(384) void pool_kernel(
    const float* __restrict__ gmean,
    unsigned* __restrict__ pooled_enc)
{
    int b = blockIdx.x, ch = blockIdx.y;
    int tid = threadIdx.x;
    const float* base = gmean + ((size_t)b * 1024 + ch * 64) * CDIM + tid;
    float m = -3.4e38f;
    for (int i = 0; i < 64; i++)
        m = fmaxf(m, base[(size_t)i * CDIM]);
    atomicMax(&pooled_enc[b * CDIM + tid], enc_f(m));
}

// ------------------------------------------------ classifier (8 blocks, validated R6+)
__global__ __launch_bounds__(384) void cls_kernel(
    const int* __restrict__ flag,
    const unsigned* __restrict__ pooled_enc,
    const float* __restrict__ Wc1, const float* __restrict__ bc1,
    const float* __restrict__ Wc2, const float* __restrict__ bc2,
    void* __restrict__ out_base)
{
    int b = blockIdx.x, t = threadIdx.x;
    __shared__ float l1[32];
    if (t < 32) l1[t] = bc1[t];
    __syncthreads();
    float v = dec_f(pooled_enc[b * CDIM + t]);
#pragma unroll
    for (int i = 0; i < 32; i++) {
        float p = v * Wc1[i * CDIM + t];
#pragma unroll
        for (int off = 32; off; off >>= 1) p += __shfl_down(p, off, 64);
        if ((t & 63) == 0) atomicAdd(&l1[i], p);
    }
    __syncthreads();
    if (t == 0) {
        float l0 = bc2[0], l1v = bc2[1];
#pragma unroll
        for (int ii = 0; ii < 32; ii++) {
            l0  += Wc2[ii] * l1[ii];
            l1v += Wc2[32 + ii] * l1[ii];
        }
        float m = fmaxf(l0, l1v);
        float e0 = __expf(l0 - m), e1 = __expf(l1v - m);
        float s = e0 + e1;
        if (*flag) {
            __hip_bfloat16* ob = (__hip_bfloat16*)out_base;
            ob[OUT_LABEL_OFF + b * 2 + 0] = __float2bfloat16(e0 / s);
            ob[OUT_LABEL_OFF + b * 2 + 1] = __float2bfloat16(e1 / s);
        } else {
            float* of = (float*)out_base;
            of[OUT_LABEL_OFF + b * 2 + 0] = e0 / s;
            of[OUT_LABEL_OFF + b * 2 + 1] = e1 / s;
        }
    }
}

extern "C" void kernel_launch(void* const* d_in, const int* in_sizes, int n_in,
                              void* d_out, int out_size, void* d_ws, size_t ws_size,
                              hipStream_t stream) {
    float* W = (float*)d_ws;
    int* flag = (int*)(W + O_FLAG);
    const int* edge_index = (const int*)d_in[1];

    prep_kernel<<<(CONV_TOTAL - O_WIH + 255) / 256, 256, 0, stream>>>(
        d_in[5], d_in[6], d_in[7], d_in[8],
        d_in[9], d_in[10], d_in[11], d_in[12], d_in[13],
        d_in[14], d_in[15], d_in[16], d_in[17], d_in[18],
        d_in[19], d_in[20], d_in[21], d_in[22], d_in[2],
        W, (unsigned short*)(W + O_WGATB), flag);

    gru_kernel<<<N_NODES / 16, 64, 0, stream>>>(
        W, d_in[0], (unsigned short*)(W + O_GATB));
    gemm_mfma<<<dim3(N_NODES / 128, NHC / 128), 256, 0, stream>>>(
        (const unsigned short*)(W + O_GATB),
        (const unsigned short*)(W + O_WGATB),
        (unsigned short*)(W + O_HFEAT),
        W + O_ATTS, W + O_ATTD,
        W + O_ASRC, W + O_ADST);
    edge_w_kernel<<<3 * E_EDGES / 256, 256, 0, stream>>>(
        edge_index, W + O_EATTR, W + O_ASRC, W + O_ADST, W + O_KH,
        W + O_WEXP, W + O_DENOM, (int*)(W + O_DEG), (int*)(W + O_BUCKET));
    aggregate_fused<<<N_NODES, 384, 0, stream>>>(
        flag, edge_index, (const unsigned short*)(W + O_HFEAT),
        W + O_WEXP, W + O_DENOM,
        (const int*)(W + O_DEG), (const int*)(W + O_BUCKET),
        W + O_GBIAS, W + O_WP1, W + O_BP1, W + O_WP3, W + O_BP3,
        W + O_GMEAN, d_out);
    pool_kernel<<<dim3(8, 16), 384, 0, stream>>>(
        W + O_GMEAN, (unsigned*)(W + O_POOLED));
    cls_kernel<<<8, 384, 0, stream>>>(
        flag, (const unsigned*)(W + O_POOLED),
        W + O_WC1, W + O_BC1, W + O_WC2, W + O_BC2, d_out);
}

// Round 14
// 227.780 us; speedup vs baseline: 1.0335x; 1.0335x over previous
//
#include <hip/hip_runtime.h>
#include <hip/hip_bf16.h>

#define N_NODES 8192
#define E_EDGES 65536
#define CDIM 384
#define NHC 1152
#define T_STEPS 12
#define PRED_LEN 6
#define OUT_LABEL_OFF 49152

#define O_X        0u
#define O_WIH      1572864u
#define O_WHH      1574400u
#define O_BIH      1577472u
#define O_BHH      1577568u
#define O_WGAT     1577664u
#define O_ATTS     2020032u
#define O_ATTD     2021184u
#define O_WEDGE    2022336u
#define O_ATTE     2023488u
#define O_GBIAS    2024640u
#define O_WP1      2025024u
#define O_BP1      2025056u
#define O_WP3      2025057u
#define O_BP3      2025129u
#define O_WC1      2025135u
#define O_BC1      2037423u
#define O_WC2      2037455u
#define O_BC2      2037519u
#define O_EATTR    2037521u
#define CONV_TOTAL 2103057u

#define O_GATIN    2103072u
#define O_GATB     O_GATIN
#define O_WGATB    (O_GATIN + 1572864u)
#define O_DEG      (O_GATIN + 1794048u)   // int [8192]
#define O_HFEAT    5248800u
#define O_ASRC     14685984u
#define O_ADST     14710560u
#define O_WEXP     14931744u
#define O_DENOM    15152928u
#define O_GMEAN    15177504u
#define O_POOLED   18323232u
#define O_KH       18326304u
#define O_FLAG     18326307u
#define O_BUCKET   18326320u              // int [8192*64]

typedef __attribute__((ext_vector_type(8))) short short8;
typedef __attribute__((ext_vector_type(4))) float floatx4;

__device__ __forceinline__ float b2f(unsigned short u) {
    return __uint_as_float(((unsigned)u) << 16);
}
__device__ __forceinline__ unsigned short f2b(float f) {
    __hip_bfloat16 b = __float2bfloat16(f);
    return *(unsigned short*)&b;
}
__device__ __forceinline__ short f2bs(float f) {
    __hip_bfloat16 b = __float2bfloat16(f);
    return *(short*)&b;
}
__device__ __forceinline__ unsigned enc_f(float f) {
    unsigned u = __float_as_uint(f);
    return (u & 0x80000000u) ? ~u : (u | 0x80000000u);
}
__device__ __forceinline__ float dec_f(unsigned e) {
    return __uint_as_float((e & 0x80000000u) ? (e & 0x7FFFFFFFu) : ~e);
}
__device__ __forceinline__ float fast_rcp(float x) {
    return __builtin_amdgcn_rcpf(x);
}

// ------------------------------------------------ prep: detect + zero + convert (x NOT converted)
__global__ __launch_bounds__(256) void prep_kernel(
    const void* Wih, const void* Whh, const void* bih, const void* bhh,
    const void* Wgat, const void* atts, const void* attd, const void* Wedge, const void* atte,
    const void* gbias, const void* Wp1, const void* bp1, const void* Wp3, const void* bp3,
    const void* Wc1, const void* bc1, const void* Wc2, const void* bc2, const void* eattr,
    float* __restrict__ W, unsigned short* __restrict__ wgatb, int* __restrict__ flag_g)
{
    __shared__ int fsh;
    if (threadIdx.x < 64) {
        int lane = threadIdx.x, cnt = 0;
#pragma unroll
        for (int i = 0; i < 8; i++) {
            unsigned short h = ((const unsigned short*)Wih)[(lane * 8 + i) * 2];
            int e = (h >> 7) & 0xFF;
            if (e >= 100 && e <= 127) cnt++;
        }
#pragma unroll
        for (int off = 32; off; off >>= 1) cnt += __shfl_down(cnt, off, 64);
        if (lane == 0) fsh = (cnt >= 300) ? 1 : 0;
    }
    __syncthreads();
    int flag = fsh;
    unsigned tidg = blockIdx.x * 256 + threadIdx.x;
    if (tidg == 0) *flag_g = flag;
    // zero: denom 24576 + pooled 3072 + deg 8192 = 35840
    if      (tidg < 24576u) W[O_DENOM + tidg] = 0.f;
    else if (tidg < 27648u) W[O_POOLED + tidg - 24576u] = 0.f;
    else if (tidg < 35840u) ((int*)(W + O_DEG))[tidg - 27648u] = 0;
    unsigned idx = tidg + O_WIH;
    if (idx >= CONV_TOTAL) return;
    if (idx >= O_WGAT && idx < O_ATTS) {
        unsigned off = idx - O_WGAT;
        wgatb[off] = flag ? ((const unsigned short*)Wgat)[off]
                          : f2b(((const float*)Wgat)[off]);
        return;
    }
    const void* src; unsigned off;
    if      (idx < O_WHH)   { src = Wih;   off = idx - O_WIH; }
    else if (idx < O_BIH)   { src = Whh;   off = idx - O_WHH; }
    else if (idx < O_BHH)   { src = bih;   off = idx - O_BIH; }
    else if (idx < O_WGAT)  { src = bhh;   off = idx - O_BHH; }
    else if (idx < O_ATTD)  { src = atts;  off = idx - O_ATTS; }
    else if (idx < O_WEDGE) { src = attd;  off = idx - O_ATTD; }
    else if (idx < O_ATTE)  { src = Wedge; off = idx - O_WEDGE; }
    else if (idx < O_GBIAS) { src = atte;  off = idx - O_ATTE; }
    else if (idx < O_WP1)   { src = gbias; off = idx - O_GBIAS; }
    else if (idx < O_BP1)   { src = Wp1;   off = idx - O_WP1; }
    else if (idx < O_BP3)   { src = (idx == O_BP1) ? bp1 : Wp3; off = (idx == O_BP1) ? 0 : idx - O_WP3; }
    else if (idx < O_WC1)   { src = bp3;   off = idx - O_BP3; }
    else if (idx < O_BC1)   { src = Wc1;   off = idx - O_WC1; }
    else if (idx < O_WC2)   { src = bc1;   off = idx - O_BC1; }
    else if (idx < O_BC2)   { src = Wc2;   off = idx - O_WC2; }
    else if (idx < O_EATTR) { src = bc2;   off = idx - O_BC2; }
    else                    { src = eattr; off = idx - O_EATTR; }
    W[idx] = flag ? b2f(((const unsigned short*)src)[off])
                  : ((const float*)src)[off];
}

// ------------------------------------------------ MFMA GRU: one wave = 16 nodes (validated R8);
// x read raw (bf16 short8 load IS the B-fragment — no conversion).
__global__ __launch_bounds__(64, 1) void gru_kernel(
    const float* __restrict__ W,
    const void* __restrict__ xraw,
    unsigned short* __restrict__ gat_b)
{
    __shared__ short hbuf[16 * 40];
    int lane = threadIdx.x;
    int q = lane >> 4, nl = lane & 15;
    int n0 = blockIdx.x * 16;
    int n = n0 + nl;
    int flag = ((const int*)(W + O_FLAG))[0];

    const float* W_wih = W + O_WIH;
    const float* W_whh = W + O_WHH;
    const float* W_bih = W + O_BIH;
    const float* W_bhh = W + O_BHH;

    short8 wh[6], wi[6];
#pragma unroll
    for (int c = 0; c < 6; c++) {
        int row = c * 16 + nl;
#pragma unroll
        for (int r = 0; r < 8; r++) {
            wh[c][r] = f2bs(W_whh[row * 32 + 8 * q + r]);
            int k = 8 * q + r;
            wi[c][r] = (k < 16) ? f2bs(W_wih[row * 16 + k]) : (short)0;
        }
    }
    float br[8], bz[8], bni[8], bnh[8];
#pragma unroll
    for (int idx = 0; idx < 8; idx++) {
        int c = idx >> 2, r = idx & 3;
        int j = c * 16 + 4 * q + r;
        br[idx]  = W_bih[j] + W_bhh[j];
        bz[idx]  = W_bih[32 + j] + W_bhh[32 + j];
        bni[idx] = W_bih[64 + j];
        bnh[idx] = W_bhh[64 + j];
    }

    floatx4 zf = {0.f, 0.f, 0.f, 0.f};
    short8 zs;
#pragma unroll
    for (int r = 0; r < 8; r++) zs[r] = 0;

    float hprev[8];
#pragma unroll
    for (int i = 0; i < 8; i++) hprev[i] = 0.f;
    short8 hfrag = zs;

    for (int t = 0; t < T_STEPS; t++) {
        short8 xf = zs;
        if (q < 2) {
            size_t xoff = (size_t)n * 192 + t * 16 + 8 * q;
            if (flag) {
                xf = *(const short8*)((const unsigned short*)xraw + xoff);
            } else {
                const float* xp = (const float*)xraw + xoff;
                float4 xa = *(const float4*)xp;
                float4 xb = *(const float4*)(xp + 4);
                xf[0] = f2bs(xa.x); xf[1] = f2bs(xa.y); xf[2] = f2bs(xa.z); xf[3] = f2bs(xa.w);
                xf[4] = f2bs(xb.x); xf[5] = f2bs(xb.y); xf[6] = f2bs(xb.z); xf[7] = f2bs(xb.w);
            }
        }

        floatx4 aR0 = __builtin_amdgcn_mfma_f32_16x16x32_bf16(wi[0], xf, zf, 0, 0, 0);
        aR0 = __builtin_amdgcn_mfma_f32_16x16x32_bf16(wh[0], hfrag, aR0, 0, 0, 0);
        floatx4 aR1 = __builtin_amdgcn_mfma_f32_16x16x32_bf16(wi[1], xf, zf, 0, 0, 0);
        aR1 = __builtin_amdgcn_mfma_f32_16x16x32_bf16(wh[1], hfrag, aR1, 0, 0, 0);
        floatx4 aZ0 = __builtin_amdgcn_mfma_f32_16x16x32_bf16(wi[2], xf, zf, 0, 0, 0);
        aZ0 = __builtin_amdgcn_mfma_f32_16x16x32_bf16(wh[2], hfrag, aZ0, 0, 0, 0);
        floatx4 aZ1 = __builtin_amdgcn_mfma_f32_16x16x32_bf16(wi[3], xf, zf, 0, 0, 0);
        aZ1 = __builtin_amdgcn_mfma_f32_16x16x32_bf16(wh[3], hfrag, aZ1, 0, 0, 0);
        floatx4 aNI0 = __builtin_amdgcn_mfma_f32_16x16x32_bf16(wi[4], xf, zf, 0, 0, 0);
        floatx4 aNI1 = __builtin_amdgcn_mfma_f32_16x16x32_bf16(wi[5], xf, zf, 0, 0, 0);
        floatx4 aNH0 = __builtin_amdgcn_mfma_f32_16x16x32_bf16(wh[4], hfrag, zf, 0, 0, 0);
        floatx4 aNH1 = __builtin_amdgcn_mfma_f32_16x16x32_bf16(wh[5], hfrag, zf, 0, 0, 0);

#pragma unroll
        for (int idx = 0; idx < 8; idx++) {
            int c = idx >> 2, r = idx & 3;
            float vR = (c ? aR1[r] : aR0[r]) + br[idx];
            float vZ = (c ? aZ1[r] : aZ0[r]) + bz[idx];
            float vNI = (c ? aNI1[r] : aNI0[r]) + bni[idx];
            float vNH = (c ? aNH1[r] : aNH0[r]) + bnh[idx];
            float rr = fast_rcp(1.f + __expf(-vR));
            float zz = fast_rcp(1.f + __expf(-vZ));
            float pre = vNI + rr * vNH;
            float e2 = __expf(2.f * pre);
            float nn = 1.f - 2.f * fast_rcp(e2 + 1.f);
            float h = (1.f - zz) * nn + zz * hprev[idx];
            hprev[idx] = h;
            int j = c * 16 + 4 * q + r;
            hbuf[nl * 40 + j] = f2bs(h);
        }
        hfrag = *(short8*)&hbuf[nl * 40 + 8 * q];
        int sn = lane >> 2, jg = (lane & 3) * 8;
        short8 hv = *(short8*)&hbuf[sn * 40 + jg];
        *(short8*)(gat_b + (size_t)(n0 + sn) * 384 + t * 32 + jg) = hv;
    }
}

// ------------------------------------------------ MFMA GEMM, bf16 output (validated R3+)
__global__ __launch_bounds__(256) void gemm_mfma(
    const unsigned short* __restrict__ Ab,
    const unsigned short* __restrict__ Bb,
    unsigned short* __restrict__ Cb)
{
    __shared__ unsigned short sA[128][40];
    __shared__ unsigned short sB[128][40];
    int tid = threadIdx.x;
    int wave = tid >> 6, lane = tid & 63;
    int wm = (wave >> 1) * 64, wn = (wave & 1) * 64;
    int m0 = blockIdx.x * 128, n0 = blockIdx.y * 128;

    int r0 = tid >> 2;
    int c8 = (tid & 3) * 8;

    floatx4 acc[4][4];
#pragma unroll
    for (int i = 0; i < 4; i++)
#pragma unroll
        for (int j = 0; j < 4; j++) acc[i][j] = 0;

    int ml = lane & 15, kq = (lane >> 4) * 8;

    for (int k0 = 0; k0 < 384; k0 += 32) {
        short8 a0 = *(const short8*)(Ab + (size_t)(m0 + r0) * 384 + k0 + c8);
        short8 a1 = *(const short8*)(Ab + (size_t)(m0 + r0 + 64) * 384 + k0 + c8);
        short8 b0 = *(const short8*)(Bb + (size_t)(n0 + r0) * 384 + k0 + c8);
        short8 b1 = *(const short8*)(Bb + (size_t)(n0 + r0 + 64) * 384 + k0 + c8);

        __syncthreads();
        *(short8*)(&sA[r0][c8])      = a0;
        *(short8*)(&sA[r0 + 64][c8]) = a1;
        *(short8*)(&sB[r0][c8])      = b0;
        *(short8*)(&sB[r0 + 64][c8]) = b1;
        __syncthreads();

        short8 af[4], bf[4];
#pragma unroll
        for (int i = 0; i < 4; i++)
            af[i] = *(const short8*)(&sA[wm + i * 16 + ml][kq]);
#pragma unroll
        for (int j = 0; j < 4; j++)
            bf[j] = *(const short8*)(&sB[wn + j * 16 + ml][kq]);
#pragma unroll
        for (int i = 0; i < 4; i++)
#pragma unroll
            for (int j = 0; j < 4; j++)
                acc[i][j] = __builtin_amdgcn_mfma_f32_16x16x32_bf16(af[i], bf[j], acc[i][j], 0, 0, 0);
    }

    int cn = lane & 15, rq = (lane >> 4) * 4;
#pragma unroll
    for (int i = 0; i < 4; i++)
#pragma unroll
        for (int j = 0; j < 4; j++)
#pragma unroll
            for (int r = 0; r < 4; r++)
                Cb[(size_t)(m0 + wm + i * 16 + rq + r) * NHC + n0 + wn + j * 16 + cn] = f2b(acc[i][j][r]);
}

// ------------------------------------------------ node attention scores (+ Kh in extra block)
__global__ __launch_bounds__(256) void att_score_kernel(
    const unsigned short* __restrict__ h_bf,
    const float* __restrict__ att_src,
    const float* __restrict__ att_dst,
    const float* __restrict__ Wedge,
    const float* __restrict__ att_edge,
    float* __restrict__ a_src, float* __restrict__ a_dst,
    float* __restrict__ Kh)
{
    if (blockIdx.x == (N_NODES * 3) / 4) {
        if (threadIdx.x < 192) {
            int hd = threadIdx.x >> 6, lane = threadIdx.x & 63;
            float s = 0.f;
#pragma unroll
            for (int qq = 0; qq < 6; qq++) {
                int c = lane + qq * 64;
                s += Wedge[hd * CDIM + c] * att_edge[hd * CDIM + c];
            }
#pragma unroll
            for (int off = 32; off; off >>= 1) s += __shfl_down(s, off, 64);
            if (lane == 0) Kh[hd] = s;
        }
        return;
    }
    int w = (blockIdx.x * 256 + threadIdx.x) >> 6;
    int lane = threadIdx.x & 63;
    int n = w / 3, hd = w % 3;
    const unsigned short* hrow = h_bf + (size_t)n * NHC + hd * CDIM;
    float s0 = 0.f, s1 = 0.f;
#pragma unroll
    for (int qq = 0; qq < 6; qq++) {
        int c = lane + qq * 64;
        float hv = b2f(hrow[c]);
        s0 += hv * att_src[hd * CDIM + c];
        s1 += hv * att_dst[hd * CDIM + c];
    }
#pragma unroll
    for (int off = 32; off; off >>= 1) {
        s0 += __shfl_down(s0, off, 64);
        s1 += __shfl_down(s1, off, 64);
    }
    if (lane == 0) { a_src[n * 3 + hd] = s0; a_dst[n * 3 + hd] = s1; }
}

// ------------------------------------------------ edge weights (exp w/o max — validated R10+)
// + denom + direct bucket fill (capacity 64; deg Poisson(8), P(>64) ~ 1e-37).
__global__ __launch_bounds__(256) void edge_w_kernel(
    const int* __restrict__ edge_index,
    const float* __restrict__ eattr,
    const float* __restrict__ a_src, const float* __restrict__ a_dst,
    const float* __restrict__ Kh,
    float* __restrict__ w_exp, float* __restrict__ denom,
    int* __restrict__ deg, int* __restrict__ bucket)
{
    int tid = blockIdx.x * 256 + threadIdx.x;
    int hd = tid >> 16;
    int e = tid & (E_EDGES - 1);
    int src = edge_index[e];
    int dst = edge_index[E_EDGES + e];
    float a = a_src[src * 3 + hd] + a_dst[dst * 3 + hd] + eattr[e] * Kh[hd];
    a = a > 0.f ? a : 0.2f * a;
    float w = __expf(a);
    w_exp[hd * E_EDGES + e] = w;
    unsafeAtomicAdd(&denom[dst * 3 + hd], w);
    if (hd == 0) {
        int pos = atomicAdd(&deg[dst], 1);
        if (pos < 64) bucket[(size_t)dst * 64 + pos] = e;
    }
}

// ------------------------------------------------ bucket aggregation + head-mean + predictor MLP
__global__ __launch_bounds__(384) void aggregate_fused(
    const int* __restrict__ flag,
    const int* __restrict__ edge_index,
    const unsigned short* __restrict__ h_bf,
    const float* __restrict__ w_exp, const float* __restrict__ denom,
    const int* __restrict__ deg, const int* __restrict__ bucket,
    const float* __restrict__ gat_bias,
    const float* __restrict__ Wp1, const float* __restrict__ bp1,
    const float* __restrict__ Wp3, const float* __restrict__ bp3,
    float* __restrict__ gmean,
    void* __restrict__ out_pred)
{
    int dst = blockIdx.x;
    int d = deg[dst]; if (d > 64) d = 64;
    int tid = threadIdx.x;
    const float third = 1.f / 3.f;
    float inv0 = third / (denom[dst * 3 + 0] + 1e-16f);
    float inv1 = third / (denom[dst * 3 + 1] + 1e-16f);
    float inv2 = third / (denom[dst * 3 + 2] + 1e-16f);
    __shared__ int ssrc[64];
    __shared__ float sc0[64], sc1[64], sc2[64];
    __shared__ float gs[384];
    __shared__ float ps[12];
    if (tid < d) {
        int e = bucket[(size_t)dst * 64 + tid];
        ssrc[tid] = edge_index[e];
        sc0[tid] = w_exp[e] * inv0;
        sc1[tid] = w_exp[E_EDGES + e] * inv1;
        sc2[tid] = w_exp[2 * E_EDGES + e] * inv2;
    }
    __syncthreads();
    float a = 0.f;
    for (int i = 0; i < d; i++) {
        const unsigned short* hs = h_bf + (size_t)ssrc[i] * NHC;
        a += sc0[i] * b2f(hs[tid]) + sc1[i] * b2f(hs[tid + CDIM]) + sc2[i] * b2f(hs[tid + 2 * CDIM]);
    }
    float g = a + gat_bias[tid];
    gmean[(size_t)dst * CDIM + tid] = g;
    gs[tid] = g;
    __syncthreads();

    int t = tid >> 5, c = tid & 31;
    float v = gs[t * 32 + c] * Wp1[c];
#pragma unroll
    for (int off = 16; off; off >>= 1) v += __shfl_down(v, off, 32);
    if (c == 0) { float p = v + bp1[0]; ps[t] = p > 0.f ? p : 0.f; }
    __syncthreads();

    if (tid < PRED_LEN) {
        float acc = bp3[tid];
#pragma unroll
        for (int tt = 0; tt < 12; tt++) acc += Wp3[tid * 12 + tt] * ps[tt];
        acc = acc > 0.f ? acc : 0.f;
        size_t oi = (size_t)dst * PRED_LEN + tid;
        if (*flag) ((__hip_bfloat16*)out_pred)[oi] = __float2bfloat16(acc);
        else       ((float*)out_pred)[oi] = acc;
    }
}

// ------------------------------------------------ two-stage batch max-pool (validated R4-R12)
__global__ __launch_bounds__(384) void pool_kernel(
    const float* __restrict__ gmean,
    unsigned* __restrict__ pooled_enc)
{
    int b = blockIdx.x, ch = blockIdx.y;
    int tid = threadIdx.x;
    const float* base = gmean + ((size_t)b * 1024 + ch * 64) * CDIM + tid;
    float m = -3.4e38f;
    for (int i = 0; i < 64; i++)
        m = fmaxf(m, base[(size_t)i * CDIM]);
    atomicMax(&pooled_enc[b * CDIM + tid], enc_f(m));
}

// ------------------------------------------------ classifier (8 blocks, validated R6-R12)
__global__ __launch_bounds__(384) void cls_kernel(
    const int* __restrict__ flag,
    const unsigned* __restrict__ pooled_enc,
    const float* __restrict__ Wc1, const float* __restrict__ bc1,
    const float* __restrict__ Wc2, const float* __restrict__ bc2,
    void* __restrict__ out_base)
{
    int b = blockIdx.x, t = threadIdx.x;
    __shared__ float l1[32];
    if (t < 32) l1[t] = bc1[t];
    __syncthreads();
    float v = dec_f(pooled_enc[b * CDIM + t]);
#pragma unroll
    for (int i = 0; i < 32; i++) {
        float p = v * Wc1[i * CDIM + t];
#pragma unroll
        for (int off = 32; off; off >>= 1) p += __shfl_down(p, off, 64);
        if ((t & 63) == 0) atomicAdd(&l1[i], p);
    }
    __syncthreads();
    if (t == 0) {
        float l0 = bc2[0], l1v = bc2[1];
#pragma unroll
        for (int ii = 0; ii < 32; ii++) {
            l0  += Wc2[ii] * l1[ii];
            l1v += Wc2[32 + ii] * l1[ii];
        }
        float m = fmaxf(l0, l1v);
        float e0 = __expf(l0 - m), e1 = __expf(l1v - m);
        float s = e0 + e1;
        if (*flag) {
            __hip_bfloat16* ob = (__hip_bfloat16*)out_base;
            ob[OUT_LABEL_OFF + b * 2 + 0] = __float2bfloat16(e0 / s);
            ob[OUT_LABEL_OFF + b * 2 + 1] = __float2bfloat16(e1 / s);
        } else {
            float* of = (float*)out_base;
            of[OUT_LABEL_OFF + b * 2 + 0] = e0 / s;
            of[OUT_LABEL_OFF + b * 2 + 1] = e1 / s;
        }
    }
}

extern "C" void kernel_launch(void* const* d_in, const int* in_sizes, int n_in,
                              void* d_out, int out_size, void* d_ws, size_t ws_size,
                              hipStream_t stream) {
    float* W = (float*)d_ws;
    int* flag = (int*)(W + O_FLAG);
    const int* edge_index = (const int*)d_in[1];

    prep_kernel<<<(CONV_TOTAL - O_WIH + 255) / 256, 256, 0, stream>>>(
        d_in[5], d_in[6], d_in[7], d_in[8],
        d_in[9], d_in[10], d_in[11], d_in[12], d_in[13],
        d_in[14], d_in[15], d_in[16], d_in[17], d_in[18],
        d_in[19], d_in[20], d_in[21], d_in[22], d_in[2],
        W, (unsigned short*)(W + O_WGATB), flag);

    gru_kernel<<<N_NODES / 16, 64, 0, stream>>>(
        W, d_in[0], (unsigned short*)(W + O_GATB));
    gemm_mfma<<<dim3(N_NODES / 128, NHC / 128), 256, 0, stream>>>(
        (const unsigned short*)(W + O_GATB),
        (const unsigned short*)(W + O_WGATB),
        (unsigned short*)(W + O_HFEAT));
    att_score_kernel<<<(N_NODES * 3) / 4 + 1, 256, 0, stream>>>(
        (const unsigned short*)(W + O_HFEAT), W + O_ATTS, W + O_ATTD,
        W + O_WEDGE, W + O_ATTE,
        W + O_ASRC, W + O_ADST, W + O_KH);
    edge_w_kernel<<<3 * E_EDGES / 256, 256, 0, stream>>>(
        edge_index, W + O_EATTR, W + O_ASRC, W + O_ADST, W + O_KH,
        W + O_WEXP, W + O_DENOM, (int*)(W + O_DEG), (int*)(W + O_BUCKET));
    aggregate_fused<<<N_NODES, 384, 0, stream>>>(
        flag, edge_index, (const unsigned short*)(W + O_HFEAT),
        W + O_WEXP, W + O_DENOM,
        (const int*)(W + O_DEG), (const int*)(W + O_BUCKET),
        W + O_GBIAS, W + O_WP1, W + O_BP1, W + O_WP3, W + O_BP3,
        W + O_GMEAN, d_out);
    pool_kernel<<<dim3(8, 16), 384, 0, stream>>>(
        W + O_GMEAN, (unsigned*)(W + O_POOLED));
    cls_kernel<<<8, 384, 0, stream>>>(
        flag, (const unsigned*)(W + O_POOLED),
        W + O_WC1, W + O_BC1, W + O_WC2, W + O_BC2, d_out);
}